// Round 8
// baseline (8376.424 us; speedup 1.0000x reference)
//
#include <hip/hip_runtime.h>

#define NELEM     16777216   // 64^4
#define WTP_PASS  36864      // 64ci * 3 * 3 * 64co
#define NFLAG     (6 * 256 * 16)
#define EX_PAR    262144     // 256 blocks * 16 px * 64 ch (one parity slot)

__device__ float    g_bufA[NELEM];      // channel-last working buffer [px][ch]
__device__ float    g_wtp[6 * WTP_PASS];
__device__ float    g_exch[2 * EX_PAR];
__device__ unsigned g_flags[NFLAG];

static __device__ __forceinline__ float ald(const float* p) {
    return __hip_atomic_load(p, __ATOMIC_RELAXED, __HIP_MEMORY_SCOPE_AGENT);
}
static __device__ __forceinline__ void ast(float* p, float v) {
    __hip_atomic_store(p, v, __ATOMIC_RELAXED, __HIP_MEMORY_SCOPE_AGENT);
}
static __device__ __forceinline__ float g4(const float4 v, int i) {
    switch (i) { case 0: return v.x; case 1: return v.y;
                 case 2: return v.z; default: return v.w; }
}

// ring cell k -> (row,col) in the 6x6 window
static __device__ __forceinline__ void kmap(int k, int& row, int& col) {
    if      (k < 4)  { row = 0;    col = k;      }
    else if (k < 8)  { row = 5;    col = k - 4;  }
    else if (k < 12) { row = k-7;  col = 0;      }
    else if (k < 16) { row = k-11; col = 5;      }
    else if (k < 18) { row = 0;    col = k - 12; }
    else             { row = 5;    col = k - 14; }
}

// Weights: g_wtp[p][((ci*3+ky)*3+kx)*64+co] (standard order for ALL passes —
// channel-last removes the per-pass spatial transpose). Also zeroes flags.
__global__ __launch_bounds__(256) void prep(
    const float* __restrict__ w0, const float* __restrict__ w1,
    const float* __restrict__ w2, const float* __restrict__ w3,
    const float* __restrict__ w4, const float* __restrict__ w5)
{
    int gid = blockIdx.x * 256 + threadIdx.x;
    if (gid < NFLAG) g_flags[gid] = 0;
    if (gid >= 6 * WTP_PASS) return;
    int p  = gid / WTP_PASS;
    int r  = gid % WTP_PASS;
    int co = r & 63;
    int q  = r >> 6;          // ci*9 + ky*3 + kx
    int kx = q % 3;
    int t2 = q / 3;
    int ky = t2 % 3;
    int ci = t2 / 3;
    const float* src = (p==0)?w0:(p==1)?w1:(p==2)?w2:(p==3)?w3:(p==4)?w4:w5;
    g_wtp[gid] = src[co*576 + ci*9 + ky*3 + kx];
}

// x [ch][px] -> A [px][ch]  (64 x 262144 transpose, tiled via LDS)
__global__ __launch_bounds__(256) void relayout_in(
    const float* __restrict__ in, float* __restrict__ out)
{
    __shared__ float t[64][65];
    const int o = blockIdx.x;          // px tile [o*64, o*64+64)
    const int c  = threadIdx.x & 63;
    const int r4 = threadIdx.x >> 6;
#pragma unroll
    for (int r = 0; r < 16; ++r) {
        int ch = r4 * 16 + r;
        t[ch][c] = in[(size_t)ch * 262144 + o * 64 + c];
    }
    __syncthreads();
#pragma unroll
    for (int r = 0; r < 16; ++r) {
        int j = r4 * 16 + r;           // px within tile
        out[((size_t)o * 64 + j) * 64 + c] = t[c][j];
    }
}

// A [px][ch] -> out [ch][px]
__global__ __launch_bounds__(256) void relayout_out(
    const float* __restrict__ in, float* __restrict__ out)
{
    __shared__ float t[64][65];
    const int o = blockIdx.x;
    const int c  = threadIdx.x & 63;
    const int r4 = threadIdx.x >> 6;
#pragma unroll
    for (int r = 0; r < 16; ++r) {
        int j = r4 * 16 + r;           // px within tile
        t[j][c] = in[((size_t)o * 64 + j) * 64 + c];
    }
    __syncthreads();
#pragma unroll
    for (int r = 0; r < 16; ++r) {
        int ch = r4 * 16 + r;
        out[(size_t)ch * 262144 + o * 64 + c] = t[c][ch];
    }
}

// Persistent per-pass scan, channel-last. Block = 4x4 px x 64 ch; 16 waves:
// wave = (ci-group g = wv&7 [8 ci], px-half h = wv>>3 [8 px]). lane = ch.
// Weights in VGPRs; own tile in LDS (rint); 20-px halo ring via coherent
// exchange; r7-proven sync protocol (wave0 polls all 8 -> B0 -> reads).
__global__ __launch_bounds__(1024, 4) void pass_kernel(
    float* __restrict__ buf, const float* __restrict__ wtp,
    unsigned* __restrict__ flags, float* __restrict__ exch,
    int stp, int sup, int svp, int dir)
{
    __shared__ float lds[21504];   // 84 KB -> exactly 1 block/CU
    float* rint = lds;             // [4 row][64 ci][4 col] own tile y[prev]
    float* ring = lds + 1024;      // [64 ci][24] halo cells (k-layout)
    float* red  = lds + 2560;      // [8 g][16 px][64 lane] partials

    const int tid  = threadIdx.x;
    const int lane = tid & 63;
    const int wv   = tid >> 6;     // 0..15
    const int g    = wv & 7;       // ci-group (8 ci)
    const int h    = wv >> 3;      // px-half (px 8h..8h+7)
    const int oiB  = 2 * h;        // output rows oiB, oiB+1
    // XCD swizzle (bijective relabel; u-row neighbors share an XCD)
    const int B  = blockIdx.x;
    const int bu = ((B & 7) << 1) | ((B >> 7) & 1);
    const int bv = (B >> 3) & 15;
    const int b  = bu * 16 + bv;
    const int u0 = bu << 2, v0 = bv << 2;
    const int row = wv >> 2, col = wv & 3;    // this wave's output px = wv

    // per-lane weights for this wave's 8 ci
    float W[8][3][3];
#pragma unroll
    for (int i = 0; i < 8; ++i)
#pragma unroll
        for (int ky = 0; ky < 3; ++ky)
#pragma unroll
            for (int kx = 0; kx < 3; ++kx)
                W[i][ky][kx] = wtp[(((g*8 + i)*3 + ky)*3 + kx)*64 + lane];

    // wave 0, lanes 0..7: one spatial neighbor flag each
    int nbr = -1;
    if (lane < 8) {
        int c  = lane + (lane >= 4 ? 1 : 0);
        int nu = bu + c/3 - 1, nv = bv + c%3 - 1;
        if (nu >= 0 && nu < 16 && nv >= 0 && nv < 16) nbr = (nu*16 + nv)*16;
    }

    // staging: wave wv owns ring cell k=wv; waves 0..3 also own k=16+wv
    int kkA = -1, soA = 0, kkB = -1, soB = 0;
#pragma unroll
    for (int j = 0; j < 2; ++j) {
        int k = (j == 0) ? wv : (wv < 4 ? 16 + wv : 99);
        if (k >= 20) continue;
        int kr, kc; kmap(k, kr, kc);
        int du = (kr==0)?-1:(kr==5)?1:0, dv = (kc==0)?-1:(kc==5)?1:0;
        int nu = bu + du, nv = bv + dv;
        if (nu < 0 || nu > 15 || nv < 0 || nv > 15) continue;
        int nb = nu*16 + nv;
        int lr = (kr==0)?3:(kr==5)?0:kr-1;
        int lc = (kc==0)?3:(kc==5)?0:kc-1;
        int so = (nb*16 + lr*4 + lc)*64 + lane;
        if (j == 0) { kkA = k; soA = so; } else { kkB = k; soB = so; }
    }

    // prologue: y[t0] own px + ring cells from buf (plain, fresh at dispatch)
    const int t0 = (dir > 0) ? 0 : 63;
    rint[(row*64 + lane)*4 + col] =
        buf[((size_t)(t0*stp + (u0+row)*sup + (v0+col)*svp) << 6) + lane];
#pragma unroll
    for (int j = 0; j < 2; ++j) {
        int k = (j == 0) ? wv : (wv < 4 ? 16 + wv : 99);
        if (k >= 20) continue;
        int kr, kc; kmap(k, kr, kc);
        int gu = u0 - 1 + kr, gv = v0 - 1 + kc;
        float v = 0.f;
        if (gu >= 0 && gu < 64 && gv >= 0 && gv < 64)
            v = buf[((size_t)(t0*stp + gu*sup + gv*svp) << 6) + lane];
        ring[lane*24 + k] = v;
    }
    __syncthreads();

    for (int s = 1; s <= 63; ++s) {
        const int t = (dir > 0) ? s : 63 - s;

        // wave 0 polls all 8 neighbor flags for step s-1 (throttled)
        if (wv == 0 && s > 1) {
            const unsigned tgt = (unsigned)(s - 1);
            bool ok = (nbr < 0);
            if (!ok) ok = __hip_atomic_load(&flags[nbr], __ATOMIC_RELAXED,
                                            __HIP_MEMORY_SCOPE_AGENT) >= tgt;
            int spins = 0;
            while (!__all(ok) && spins < (1 << 22)) {
                __builtin_amdgcn_s_sleep(1);
                if (!ok) ok = __hip_atomic_load(&flags[nbr], __ATOMIC_RELAXED,
                                                __HIP_MEMORY_SCOPE_AGENT) >= tgt;
                ++spins;
            }
        }
        __syncthreads();   // B0: all neighbor halos for step s-1 published

        // x[t] prefetch (plain cached; only this thread ever writes this addr)
        const size_t oaddr =
            ((size_t)(t*stp + (u0+row)*sup + (v0+col)*svp) << 6) + lane;
        const float xv = buf[oaddr];

        // issue exchange loads now (latency overlaps PhaseA)
        float cA = 0.f, cB = 0.f;
        if (s > 1) {
            const float* xsrc = exch + (size_t)((s-1) & 1) * EX_PAR;
            if (kkA >= 0) cA = ald(xsrc + soA);
            if (kkB >= 0) cB = ald(xsrc + soB);
        }

        float acc[8];
#pragma unroll
        for (int p = 0; p < 8; ++p) acc[p] = 0.f;

        // PHASE A: own-tile taps (wr,wc in [1,4]); rows rowStart..rowStart+2
        const int rowStart = h;   // h=0 -> rint rows 0..2; h=1 -> rows 1..3
#pragma unroll
        for (int i = 0; i < 8; ++i) {
            const int ci = g*8 + i;
            const float4 R0 = *(const float4*)&rint[((rowStart+0)*64 + ci)*4];
            const float4 R1 = *(const float4*)&rint[((rowStart+1)*64 + ci)*4];
            const float4 R2 = *(const float4*)&rint[((rowStart+2)*64 + ci)*4];
#pragma unroll
            for (int lp = 0; lp < 2; ++lp) {
                const int oi = oiB + lp;
#pragma unroll
                for (int ky = 0; ky < 3; ++ky) {
                    const int wr = oi + ky;
                    if (wr < 1 || wr > 4) continue;
                    const int ri = wr - 1 - rowStart;   // 0..2
                    const float4 Rw = (ri == 0) ? R0 : (ri == 1) ? R1 : R2;
#pragma unroll
                    for (int oj = 0; oj < 4; ++oj)
#pragma unroll
                    for (int kx = 0; kx < 3; ++kx) {
                        const int wc = oj + kx;
                        if (wc < 1 || wc > 4) continue;
                        acc[lp*4+oj] = fmaf(W[i][ky][kx], g4(Rw, wc-1),
                                            acc[lp*4+oj]);
                    }
                }
            }
        }

        // land staged ring cells (exchange loads have drained under PhaseA)
        if (s > 1) {
            if (kkA >= 0) ring[lane*24 + kkA] = cA;
            if (kkB >= 0) ring[lane*24 + kkB] = cB;
        }
        __syncthreads();   // B1: ring complete

        // PHASE B: ring taps for this px-half
#pragma unroll
        for (int i = 0; i < 8; ++i) {
            const int ci = g*8 + i;
            const float4 r0a = *(const float4*)&ring[ci*24 + 0];
            const float4 r5a = *(const float4*)&ring[ci*24 + 4];
            const float4 cl  = *(const float4*)&ring[ci*24 + 8];
            const float4 cr  = *(const float4*)&ring[ci*24 + 12];
            const float2 r0b = *(const float2*)&ring[ci*24 + 16];
            const float2 r5b = *(const float2*)&ring[ci*24 + 18];
#pragma unroll
            for (int lp = 0; lp < 2; ++lp) {
                const int oi = oiB + lp;
#pragma unroll
                for (int ky = 0; ky < 3; ++ky) {
                    const int wr = oi + ky;
#pragma unroll
                    for (int oj = 0; oj < 4; ++oj)
#pragma unroll
                    for (int kx = 0; kx < 3; ++kx) {
                        const int wc = oj + kx;
                        if (wr >= 1 && wr <= 4 && wc >= 1 && wc <= 4) continue;
                        float cell;
                        if      (wr == 0) cell = (wc < 4) ? g4(r0a, wc)
                                                 : (wc == 4 ? r0b.x : r0b.y);
                        else if (wr == 5) cell = (wc < 4) ? g4(r5a, wc)
                                                 : (wc == 4 ? r5b.x : r5b.y);
                        else if (wc == 0) cell = g4(cl, wr-1);
                        else              cell = g4(cr, wr-1);
                        acc[lp*4+oj] = fmaf(W[i][ky][kx], cell, acc[lp*4+oj]);
                    }
                }
            }
        }

        // partials -> LDS: wave (g,h) wrote px 8h+lp*4+oj
#pragma unroll
        for (int p = 0; p < 8; ++p)
            red[(g*16 + 8*h + p)*64 + lane] = acc[p];
        __syncthreads();   // B2

        // wave wv reduces its own px (= wv)
        float sum = 0.f;
#pragma unroll
        for (int g2 = 0; g2 < 8; ++g2)
            sum += red[(g2*16 + wv)*64 + lane];
        const float o = xv + fmaxf(sum, 0.f);

        buf[oaddr] = o;                         // plain store (read next pass)
        if (s < 63) {
            rint[(row*64 + lane)*4 + col] = o;  // next step's own tile
            ast(exch + (size_t)(s & 1)*EX_PAR + b*1024 + wv*64 + lane, o);
        }
        __syncthreads();   // B3: drains all waves' stores before flag publish

        if (s < 63 && tid == 0)
            __hip_atomic_store(&flags[b*16], (unsigned)s, __ATOMIC_RELAXED,
                               __HIP_MEMORY_SCOPE_AGENT);
    }
}

extern "C" void kernel_launch(void* const* d_in, const int* in_sizes, int n_in,
                              void* d_out, int out_size, void* d_ws, size_t ws_size,
                              hipStream_t stream)
{
    (void)in_sizes; (void)n_in; (void)out_size; (void)d_ws; (void)ws_size;
    const float* x = (const float*)d_in[0];
    float* out = (float*)d_out;

    void *pa, *pw, *pf, *pe;
    hipGetSymbolAddress(&pa, HIP_SYMBOL(g_bufA));
    hipGetSymbolAddress(&pw, HIP_SYMBOL(g_wtp));
    hipGetSymbolAddress(&pf, HIP_SYMBOL(g_flags));
    hipGetSymbolAddress(&pe, HIP_SYMBOL(g_exch));
    float* A = (float*)pa;
    float* wtp = (float*)pw;
    unsigned* flags = (unsigned*)pf;
    float* exch = (float*)pe;

    prep<<<864, 256, 0, stream>>>(
        (const float*)d_in[1], (const float*)d_in[2], (const float*)d_in[3],
        (const float*)d_in[4], (const float*)d_in[5], (const float*)d_in[6]);

    relayout_in<<<4096, 256, 0, stream>>>(x, A);   // -> channel-last [d][h][w][ch]

    // px-unit strides: d=4096, h=64, w=1 (channel stride handled by <<6)
    // UD/DU: t=h, u=d, v=w
    pass_kernel<<<256, 1024, 0, stream>>>(A, wtp + 0*WTP_PASS, flags + 0*4096, exch, 64, 4096, 1, +1);
    pass_kernel<<<256, 1024, 0, stream>>>(A, wtp + 1*WTP_PASS, flags + 1*4096, exch, 64, 4096, 1, -1);
    // LR/RL: t=w, u=d, v=h
    pass_kernel<<<256, 1024, 0, stream>>>(A, wtp + 2*WTP_PASS, flags + 2*4096, exch, 1, 4096, 64, +1);
    pass_kernel<<<256, 1024, 0, stream>>>(A, wtp + 3*WTP_PASS, flags + 3*4096, exch, 1, 4096, 64, -1);
    // FB/BF: t=d, u=h, v=w
    pass_kernel<<<256, 1024, 0, stream>>>(A, wtp + 4*WTP_PASS, flags + 4*4096, exch, 4096, 64, 1, +1);
    pass_kernel<<<256, 1024, 0, stream>>>(A, wtp + 5*WTP_PASS, flags + 5*4096, exch, 4096, 64, 1, -1);

    relayout_out<<<4096, 256, 0, stream>>>(A, out);  // -> [ch][d][h][w]
}

// Round 9
// 8373.600 us; speedup vs baseline: 1.0003x; 1.0003x over previous
//
#include <hip/hip_runtime.h>

#define NELEM     16777216   // 64^4
#define WTP_PASS  36864      // 64ci * 3 * 3 * 64co
#define NFLAG     (6 * 256 * 16)
#define EX_PAR    262144     // 256 blocks * 16 px * 64 ch (one parity slot)

__device__ float    g_bufA[NELEM];      // channel-last working buffer [px][ch]
__device__ float    g_wtp[6 * WTP_PASS];
__device__ float    g_exch[2 * EX_PAR];
__device__ unsigned g_flags[NFLAG];

static __device__ __forceinline__ float ald(const float* p) {
    return __hip_atomic_load(p, __ATOMIC_RELAXED, __HIP_MEMORY_SCOPE_AGENT);
}
static __device__ __forceinline__ void ast(float* p, float v) {
    __hip_atomic_store(p, v, __ATOMIC_RELAXED, __HIP_MEMORY_SCOPE_AGENT);
}
static __device__ __forceinline__ float g4(const float4 v, int i) {
    switch (i) { case 0: return v.x; case 1: return v.y;
                 case 2: return v.z; default: return v.w; }
}

// ring cell k -> (row,col) in the 6x6 window
static __device__ __forceinline__ void kmap(int k, int& row, int& col) {
    if      (k < 4)  { row = 0;    col = k;      }
    else if (k < 8)  { row = 5;    col = k - 4;  }
    else if (k < 12) { row = k-7;  col = 0;      }
    else if (k < 16) { row = k-11; col = 5;      }
    else if (k < 18) { row = 0;    col = k - 12; }
    else             { row = 5;    col = k - 14; }
}

// Weights: g_wtp[p][((ci*3+ky)*3+kx)*64+co] (standard order for ALL passes —
// channel-last removes the per-pass spatial transpose). Also zeroes flags.
__global__ __launch_bounds__(256) void prep(
    const float* __restrict__ w0, const float* __restrict__ w1,
    const float* __restrict__ w2, const float* __restrict__ w3,
    const float* __restrict__ w4, const float* __restrict__ w5)
{
    int gid = blockIdx.x * 256 + threadIdx.x;
    if (gid < NFLAG) g_flags[gid] = 0;
    if (gid >= 6 * WTP_PASS) return;
    int p  = gid / WTP_PASS;
    int r  = gid % WTP_PASS;
    int co = r & 63;
    int q  = r >> 6;          // ci*9 + ky*3 + kx
    int kx = q % 3;
    int t2 = q / 3;
    int ky = t2 % 3;
    int ci = t2 / 3;
    const float* src = (p==0)?w0:(p==1)?w1:(p==2)?w2:(p==3)?w3:(p==4)?w4:w5;
    g_wtp[gid] = src[co*576 + ci*9 + ky*3 + kx];
}

// x [ch][px] -> A [px][ch]  (64 x 262144 transpose, tiled via LDS)
__global__ __launch_bounds__(256) void relayout_in(
    const float* __restrict__ in, float* __restrict__ out)
{
    __shared__ float t[64][65];
    const int o = blockIdx.x;          // px tile [o*64, o*64+64)
    const int c  = threadIdx.x & 63;
    const int r4 = threadIdx.x >> 6;
#pragma unroll
    for (int r = 0; r < 16; ++r) {
        int ch = r4 * 16 + r;
        t[ch][c] = in[(size_t)ch * 262144 + o * 64 + c];
    }
    __syncthreads();
#pragma unroll
    for (int r = 0; r < 16; ++r) {
        int j = r4 * 16 + r;           // px within tile
        out[((size_t)o * 64 + j) * 64 + c] = t[c][j];
    }
}

// A [px][ch] -> out [ch][px]
__global__ __launch_bounds__(256) void relayout_out(
    const float* __restrict__ in, float* __restrict__ out)
{
    __shared__ float t[64][65];
    const int o = blockIdx.x;
    const int c  = threadIdx.x & 63;
    const int r4 = threadIdx.x >> 6;
#pragma unroll
    for (int r = 0; r < 16; ++r) {
        int j = r4 * 16 + r;           // px within tile
        t[j][c] = in[((size_t)o * 64 + j) * 64 + c];
    }
    __syncthreads();
#pragma unroll
    for (int r = 0; r < 16; ++r) {
        int ch = r4 * 16 + r;
        out[(size_t)ch * 262144 + o * 64 + c] = t[c][ch];
    }
}

// Persistent per-pass scan, channel-last. Block = 4x4 px x 64 ch; 16 waves:
// wave = (ci-group g = wv&7 [8 ci], px-half h = wv>>3 [8 px]). lane = ch.
// Weights in VGPRs; own tile in LDS (rint); 20-px halo ring via coherent
// exchange; r7-proven sync protocol (wave0 polls all 8 -> B0 -> reads).
// launch_bounds (1024, 2): min-2-waves/EU keeps the VGPR cap at 256 so the
// 72-VGPR weight array is NOT spilled (r8's (1024,4) -> 64 VGPR -> 3.4 GB
// of scratch traffic). Residency (4 waves/SIMD) comes from the 84 KB LDS pad.
__global__ __launch_bounds__(1024, 2) void pass_kernel(
    float* __restrict__ buf, const float* __restrict__ wtp,
    unsigned* __restrict__ flags, float* __restrict__ exch,
    int stp, int sup, int svp, int dir)
{
    __shared__ float lds[21504];   // 84 KB -> exactly 1 block/CU
    float* rint = lds;             // [4 row][64 ci][4 col] own tile y[prev]
    float* ring = lds + 1024;      // [64 ci][24] halo cells (k-layout)
    float* red  = lds + 2560;      // [8 g][16 px][64 lane] partials

    const int tid  = threadIdx.x;
    const int lane = tid & 63;
    const int wv   = tid >> 6;     // 0..15
    const int g    = wv & 7;       // ci-group (8 ci)
    const int h    = wv >> 3;      // px-half (px 8h..8h+7)
    const int oiB  = 2 * h;        // output rows oiB, oiB+1
    // XCD swizzle (bijective relabel; u-row neighbors share an XCD)
    const int B  = blockIdx.x;
    const int bu = ((B & 7) << 1) | ((B >> 7) & 1);
    const int bv = (B >> 3) & 15;
    const int b  = bu * 16 + bv;
    const int u0 = bu << 2, v0 = bv << 2;
    const int row = wv >> 2, col = wv & 3;    // this wave's output px = wv

    // per-lane weights for this wave's 8 ci
    float W[8][3][3];
#pragma unroll
    for (int i = 0; i < 8; ++i)
#pragma unroll
        for (int ky = 0; ky < 3; ++ky)
#pragma unroll
            for (int kx = 0; kx < 3; ++kx)
                W[i][ky][kx] = wtp[(((g*8 + i)*3 + ky)*3 + kx)*64 + lane];

    // wave 0, lanes 0..7: one spatial neighbor flag each
    int nbr = -1;
    if (lane < 8) {
        int c  = lane + (lane >= 4 ? 1 : 0);
        int nu = bu + c/3 - 1, nv = bv + c%3 - 1;
        if (nu >= 0 && nu < 16 && nv >= 0 && nv < 16) nbr = (nu*16 + nv)*16;
    }

    // staging: wave wv owns ring cell k=wv; waves 0..3 also own k=16+wv
    int kkA = -1, soA = 0, kkB = -1, soB = 0;
#pragma unroll
    for (int j = 0; j < 2; ++j) {
        int k = (j == 0) ? wv : (wv < 4 ? 16 + wv : 99);
        if (k >= 20) continue;
        int kr, kc; kmap(k, kr, kc);
        int du = (kr==0)?-1:(kr==5)?1:0, dv = (kc==0)?-1:(kc==5)?1:0;
        int nu = bu + du, nv = bv + dv;
        if (nu < 0 || nu > 15 || nv < 0 || nv > 15) continue;
        int nb = nu*16 + nv;
        int lr = (kr==0)?3:(kr==5)?0:kr-1;
        int lc = (kc==0)?3:(kc==5)?0:kc-1;
        int so = (nb*16 + lr*4 + lc)*64 + lane;
        if (j == 0) { kkA = k; soA = so; } else { kkB = k; soB = so; }
    }

    // prologue: y[t0] own px + ring cells from buf (plain, fresh at dispatch)
    const int t0 = (dir > 0) ? 0 : 63;
    rint[(row*64 + lane)*4 + col] =
        buf[((size_t)(t0*stp + (u0+row)*sup + (v0+col)*svp) << 6) + lane];
#pragma unroll
    for (int j = 0; j < 2; ++j) {
        int k = (j == 0) ? wv : (wv < 4 ? 16 + wv : 99);
        if (k >= 20) continue;
        int kr, kc; kmap(k, kr, kc);
        int gu = u0 - 1 + kr, gv = v0 - 1 + kc;
        float v = 0.f;
        if (gu >= 0 && gu < 64 && gv >= 0 && gv < 64)
            v = buf[((size_t)(t0*stp + gu*sup + gv*svp) << 6) + lane];
        ring[lane*24 + k] = v;
    }
    __syncthreads();

    for (int s = 1; s <= 63; ++s) {
        const int t = (dir > 0) ? s : 63 - s;

        // wave 0 polls all 8 neighbor flags for step s-1 (throttled)
        if (wv == 0 && s > 1) {
            const unsigned tgt = (unsigned)(s - 1);
            bool ok = (nbr < 0);
            if (!ok) ok = __hip_atomic_load(&flags[nbr], __ATOMIC_RELAXED,
                                            __HIP_MEMORY_SCOPE_AGENT) >= tgt;
            int spins = 0;
            while (!__all(ok) && spins < (1 << 22)) {
                __builtin_amdgcn_s_sleep(1);
                if (!ok) ok = __hip_atomic_load(&flags[nbr], __ATOMIC_RELAXED,
                                                __HIP_MEMORY_SCOPE_AGENT) >= tgt;
                ++spins;
            }
        }
        __syncthreads();   // B0: all neighbor halos for step s-1 published

        // x[t] prefetch (plain cached; only this thread ever writes this addr)
        const size_t oaddr =
            ((size_t)(t*stp + (u0+row)*sup + (v0+col)*svp) << 6) + lane;
        const float xv = buf[oaddr];

        // issue exchange loads now (latency overlaps PhaseA)
        float cA = 0.f, cB = 0.f;
        if (s > 1) {
            const float* xsrc = exch + (size_t)((s-1) & 1) * EX_PAR;
            if (kkA >= 0) cA = ald(xsrc + soA);
            if (kkB >= 0) cB = ald(xsrc + soB);
        }

        float acc[8];
#pragma unroll
        for (int p = 0; p < 8; ++p) acc[p] = 0.f;

        // PHASE A: own-tile taps (wr,wc in [1,4]); rows rowStart..rowStart+2
        const int rowStart = h;   // h=0 -> rint rows 0..2; h=1 -> rows 1..3
#pragma unroll
        for (int i = 0; i < 8; ++i) {
            const int ci = g*8 + i;
            const float4 R0 = *(const float4*)&rint[((rowStart+0)*64 + ci)*4];
            const float4 R1 = *(const float4*)&rint[((rowStart+1)*64 + ci)*4];
            const float4 R2 = *(const float4*)&rint[((rowStart+2)*64 + ci)*4];
#pragma unroll
            for (int lp = 0; lp < 2; ++lp) {
                const int oi = oiB + lp;
#pragma unroll
                for (int ky = 0; ky < 3; ++ky) {
                    const int wr = oi + ky;
                    if (wr < 1 || wr > 4) continue;
                    const int ri = wr - 1 - rowStart;   // 0..2
                    const float4 Rw = (ri == 0) ? R0 : (ri == 1) ? R1 : R2;
#pragma unroll
                    for (int oj = 0; oj < 4; ++oj)
#pragma unroll
                    for (int kx = 0; kx < 3; ++kx) {
                        const int wc = oj + kx;
                        if (wc < 1 || wc > 4) continue;
                        acc[lp*4+oj] = fmaf(W[i][ky][kx], g4(Rw, wc-1),
                                            acc[lp*4+oj]);
                    }
                }
            }
        }

        // land staged ring cells (exchange loads have drained under PhaseA)
        if (s > 1) {
            if (kkA >= 0) ring[lane*24 + kkA] = cA;
            if (kkB >= 0) ring[lane*24 + kkB] = cB;
        }
        __syncthreads();   // B1: ring complete

        // PHASE B: ring taps for this px-half
#pragma unroll
        for (int i = 0; i < 8; ++i) {
            const int ci = g*8 + i;
            const float4 r0a = *(const float4*)&ring[ci*24 + 0];
            const float4 r5a = *(const float4*)&ring[ci*24 + 4];
            const float4 cl  = *(const float4*)&ring[ci*24 + 8];
            const float4 cr  = *(const float4*)&ring[ci*24 + 12];
            const float2 r0b = *(const float2*)&ring[ci*24 + 16];
            const float2 r5b = *(const float2*)&ring[ci*24 + 18];
#pragma unroll
            for (int lp = 0; lp < 2; ++lp) {
                const int oi = oiB + lp;
#pragma unroll
                for (int ky = 0; ky < 3; ++ky) {
                    const int wr = oi + ky;
#pragma unroll
                    for (int oj = 0; oj < 4; ++oj)
#pragma unroll
                    for (int kx = 0; kx < 3; ++kx) {
                        const int wc = oj + kx;
                        if (wr >= 1 && wr <= 4 && wc >= 1 && wc <= 4) continue;
                        float cell;
                        if      (wr == 0) cell = (wc < 4) ? g4(r0a, wc)
                                                 : (wc == 4 ? r0b.x : r0b.y);
                        else if (wr == 5) cell = (wc < 4) ? g4(r5a, wc)
                                                 : (wc == 4 ? r5b.x : r5b.y);
                        else if (wc == 0) cell = g4(cl, wr-1);
                        else              cell = g4(cr, wr-1);
                        acc[lp*4+oj] = fmaf(W[i][ky][kx], cell, acc[lp*4+oj]);
                    }
                }
            }
        }

        // partials -> LDS: wave (g,h) wrote px 8h+lp*4+oj
#pragma unroll
        for (int p = 0; p < 8; ++p)
            red[(g*16 + 8*h + p)*64 + lane] = acc[p];
        __syncthreads();   // B2

        // wave wv reduces its own px (= wv)
        float sum = 0.f;
#pragma unroll
        for (int g2 = 0; g2 < 8; ++g2)
            sum += red[(g2*16 + wv)*64 + lane];
        const float o = xv + fmaxf(sum, 0.f);

        buf[oaddr] = o;                         // plain store (read next pass)
        if (s < 63) {
            rint[(row*64 + lane)*4 + col] = o;  // next step's own tile
            ast(exch + (size_t)(s & 1)*EX_PAR + b*1024 + wv*64 + lane, o);
        }
        __syncthreads();   // B3: drains all waves' stores before flag publish

        if (s < 63 && tid == 0)
            __hip_atomic_store(&flags[b*16], (unsigned)s, __ATOMIC_RELAXED,
                               __HIP_MEMORY_SCOPE_AGENT);
    }
}

extern "C" void kernel_launch(void* const* d_in, const int* in_sizes, int n_in,
                              void* d_out, int out_size, void* d_ws, size_t ws_size,
                              hipStream_t stream)
{
    (void)in_sizes; (void)n_in; (void)out_size; (void)d_ws; (void)ws_size;
    const float* x = (const float*)d_in[0];
    float* out = (float*)d_out;

    void *pa, *pw, *pf, *pe;
    hipGetSymbolAddress(&pa, HIP_SYMBOL(g_bufA));
    hipGetSymbolAddress(&pw, HIP_SYMBOL(g_wtp));
    hipGetSymbolAddress(&pf, HIP_SYMBOL(g_flags));
    hipGetSymbolAddress(&pe, HIP_SYMBOL(g_exch));
    float* A = (float*)pa;
    float* wtp = (float*)pw;
    unsigned* flags = (unsigned*)pf;
    float* exch = (float*)pe;

    prep<<<864, 256, 0, stream>>>(
        (const float*)d_in[1], (const float*)d_in[2], (const float*)d_in[3],
        (const float*)d_in[4], (const float*)d_in[5], (const float*)d_in[6]);

    relayout_in<<<4096, 256, 0, stream>>>(x, A);   // -> channel-last [d][h][w][ch]

    // px-unit strides: d=4096, h=64, w=1 (channel stride handled by <<6)
    // UD/DU: t=h, u=d, v=w
    pass_kernel<<<256, 1024, 0, stream>>>(A, wtp + 0*WTP_PASS, flags + 0*4096, exch, 64, 4096, 1, +1);
    pass_kernel<<<256, 1024, 0, stream>>>(A, wtp + 1*WTP_PASS, flags + 1*4096, exch, 64, 4096, 1, -1);
    // LR/RL: t=w, u=d, v=h
    pass_kernel<<<256, 1024, 0, stream>>>(A, wtp + 2*WTP_PASS, flags + 2*4096, exch, 1, 4096, 64, +1);
    pass_kernel<<<256, 1024, 0, stream>>>(A, wtp + 3*WTP_PASS, flags + 3*4096, exch, 1, 4096, 64, -1);
    // FB/BF: t=d, u=h, v=w
    pass_kernel<<<256, 1024, 0, stream>>>(A, wtp + 4*WTP_PASS, flags + 4*4096, exch, 4096, 64, 1, +1);
    pass_kernel<<<256, 1024, 0, stream>>>(A, wtp + 5*WTP_PASS, flags + 5*4096, exch, 4096, 64, 1, -1);

    relayout_out<<<4096, 256, 0, stream>>>(A, out);  // -> [ch][d][h][w]
}